// Round 21
// baseline (70.578 us; speedup 1.0000x reference)
//
#include <hip/hip_runtime.h>
#include <hip/hip_bf16.h>
#include <math.h>

// Problem constants (match reference)
#define BB      8
#define C_CH    128
#define HH      256
#define WW      256
#define N_POS   2048
#define N_NEG   8192
#define N_ROWS  (N_POS + N_NEG)     // 10240
#define EPS_N   1e-6f

// sim tiling (THIS round): block = 8 waves (512 thr) as 4(i) x 2(j):
// T_i = 256 rows, T_j = 128 cols; BOTH j-slabs' B staged to LDS (64 KB).
// Halves A-stream passes vs r19: traffic 210 -> 126 MB.
#define NIG     (N_POS / 256)       // 8   i-groups
#define NJG     (N_ROWS / 128)      // 80  j-groups (2 slabs each)
#define NJS     (N_ROWS / 64)       // 160
#define NJSLAB      (N_ROWS / 64)   // 160
#define NJSLAB_POS  (N_POS / 64)    // 32

// Fragment-swizzled operand layout (r17, confirmed win):
#define PANEL   512                  // shorts per (tile,ks) panel

typedef __attribute__((ext_vector_type(8))) short bf16x8;
typedef __attribute__((ext_vector_type(4))) float f32x4;

// Workspace:
//   hi_t: [640][4][64][8] bf16 (2.62 MB) | lo_t: same | partial (1.31 MB)
//   bsum[8] f32

// ---------------------------------------------------------------------------
// Kernel 1: gather + L2-normalize + split to bf16 hi/lo (swizzled out).
// UNCHANGED (r17/r19 form).
__global__ __launch_bounds__(256) void gather_norm_kernel(
    const float* __restrict__ seg,
    const int* __restrict__ pb, const int* __restrict__ ph, const int* __restrict__ pw,
    const int* __restrict__ nb, const int* __restrict__ nh, const int* __restrict__ nw,
    ushort* __restrict__ hi_t, ushort* __restrict__ lo_t)
{
    const int wave = threadIdx.x >> 6;
    const int lane = threadIdx.x & 63;
    const int row  = blockIdx.x * 4 + wave;
    if (row >= N_ROWS) return;

    int b, h, w;
    if (row < N_POS) { b = pb[row]; h = ph[row]; w = pw[row]; }
    else { const int r = row - N_POS; b = nb[r]; h = nh[r]; w = nw[r]; }

    const size_t cs   = (size_t)HH * WW;
    const size_t base = (size_t)b * C_CH * cs + (size_t)h * WW + (size_t)w;

    const float v0 = seg[base + (size_t)lane * cs];
    const float v1 = seg[base + (size_t)(lane + 64) * cs];

    float ss = v0 * v0 + v1 * v1;
#pragma unroll
    for (int m = 1; m < 64; m <<= 1) ss += __shfl_xor(ss, m, 64);

    const float n  = fmaxf(sqrtf(ss), EPS_N);
    const float u0 = v0 / n;
    const float u1 = v1 / n;

    const __hip_bfloat16 h0 = __float2bfloat16(u0);
    const __hip_bfloat16 h1 = __float2bfloat16(u1);
    const __hip_bfloat16 l0 = __float2bfloat16(u0 - __bfloat162float(h0));
    const __hip_bfloat16 l1 = __float2bfloat16(u1 - __bfloat162float(h1));

    const int tile = row >> 4;
    const int lr   = row & 15;

    const int e0 = lane;
    const int ks0 = e0 >> 5, lk0 = (e0 & 31) >> 3, ke0 = e0 & 7;
    const size_t o0 = ((size_t)(tile * 4 + ks0) * 64 + lk0 * 16 + lr) * 8 + ke0;

    const int e1 = lane + 64;
    const int ks1 = e1 >> 5, lk1 = (e1 & 31) >> 3, ke1 = e1 & 7;
    const size_t o1 = ((size_t)(tile * 4 + ks1) * 64 + lk1 * 16 + lr) * 8 + ke1;

    hi_t[o0] = __hip_bfloat16_raw(h0).x;  lo_t[o0] = __hip_bfloat16_raw(l0).x;
    hi_t[o1] = __hip_bfloat16_raw(h1).x;  lo_t[o1] = __hip_bfloat16_raw(l1).x;
}

// ---------------------------------------------------------------------------
// Kernel 2: split-bf16 MFMA sim. 8 waves = 4 i-tiles x 2 j-slabs; both
// j-slabs' B panels staged to LDS once (64 KB, one barrier). A fragments
// stream from global (swizzled, contiguous, batched); B per-n from LDS
// (keeps VGPR <= ~128 for 2 blocks/CU = 16 waves).
__global__ __launch_bounds__(512) void sim_mfma_kernel(
    const ushort* __restrict__ hi_t, const ushort* __restrict__ lo_t,
    float* __restrict__ partial)
{
    __shared__ ushort ldsB[2][2][8192];   // [slab][hi/lo][16 KB] = 64 KB

    const int bid = blockIdx.x;
    const int ig  = bid / NJG;          // 0..7   (256-row i-group)
    const int jsg = bid % NJG;          // 0..79  (same-jsg blocks == mod 8 -> same XCD)
    const int t    = threadIdx.x;
    const int wv   = t >> 6;
    const int ln   = t & 63;
    const int wy   = wv & 3;            // i-tile within group (64 rows)
    const int wx   = wv >> 2;           // j-slab within pair

    // ---- stage both j-slabs' B panels: 4 x 16 KB linear copies ----
    {
        const size_t gb0 = (size_t)(jsg * 2 + 0) * 8192;
        const size_t gb1 = (size_t)(jsg * 2 + 1) * 8192;
#pragma unroll
        for (int c = 0; c < 2; ++c) {
            const int off = (c * 512 + t) * 8;   // 8 shorts = 16B per thread
            *(bf16x8*)&ldsB[0][0][off] = *(const bf16x8*)&hi_t[gb0 + off];
            *(bf16x8*)&ldsB[0][1][off] = *(const bf16x8*)&lo_t[gb0 + off];
            *(bf16x8*)&ldsB[1][0][off] = *(const bf16x8*)&hi_t[gb1 + off];
            *(bf16x8*)&ldsB[1][1][off] = *(const bf16x8*)&lo_t[gb1 + off];
        }
    }
    __syncthreads();

    const int js  = jsg * 2 + wx;       // 0..159
    const int iw0 = ig * 256 + wy * 64;
    const int lr = ln & 15;
    const int lk = ln >> 4;

    f32x4 acc[4][4];
#pragma unroll
    for (int m = 0; m < 4; ++m)
#pragma unroll
        for (int n = 0; n < 4; ++n) acc[m][n] = (f32x4){0.f, 0.f, 0.f, 0.f};

#pragma unroll
    for (int ks = 0; ks < 4; ++ks) {
        bf16x8 ah[4], al[4];
#pragma unroll
        for (int m = 0; m < 4; ++m) {
            // A tile index: ig*16 + wy*4 + m
            const size_t pa = ((size_t)((ig * 16 + wy * 4 + m) * 4 + ks)) * PANEL + ln * 8;
            ah[m] = *(const bf16x8*)&hi_t[pa];
            al[m] = *(const bf16x8*)&lo_t[pa];
        }
#pragma unroll
        for (int n = 0; n < 4; ++n) {
            const int lo_off = (n * 4 + ks) * PANEL + ln * 8;
            const bf16x8 bh = *(const bf16x8*)&ldsB[wx][0][lo_off];
            const bf16x8 bl = *(const bf16x8*)&ldsB[wx][1][lo_off];
#pragma unroll
            for (int m = 0; m < 4; ++m) {
                acc[m][n] = __builtin_amdgcn_mfma_f32_16x16x32_bf16(ah[m], bh, acc[m][n], 0, 0, 0);
                acc[m][n] = __builtin_amdgcn_mfma_f32_16x16x32_bf16(ah[m], bl, acc[m][n], 0, 0, 0);
                acc[m][n] = __builtin_amdgcn_mfma_f32_16x16x32_bf16(al[m], bh, acc[m][n], 0, 0, 0);
            }
        }
    }

    // Epilogue. value r of lane l = C[iw0+m*16+(l>>4)*4+r][js*64+n*16+(l&15)]
#pragma unroll
    for (int m = 0; m < 4; ++m) {
        float s0 = 0.f, s1 = 0.f, s2 = 0.f, s3 = 0.f;
#pragma unroll
        for (int n = 0; n < 4; ++n) {
            s0 += expf(acc[m][n][0]);
            s1 += expf(acc[m][n][1]);
            s2 += expf(acc[m][n][2]);
            s3 += expf(acc[m][n][3]);
        }
        float s[4] = {s0, s1, s2, s3};
#pragma unroll
        for (int r = 0; r < 4; ++r) {
            float v = s[r];
            v += __shfl_xor(v, 1, 64);
            v += __shfl_xor(v, 2, 64);
            v += __shfl_xor(v, 4, 64);
            v += __shfl_xor(v, 8, 64);
            if (lr == 0) {
                const int row = iw0 + m * 16 + lk * 4 + r;
                partial[(size_t)js * N_POS + row] = v;   // single writer
            }
        }
    }
}

// ---------------------------------------------------------------------------
// Kernel 3a: per-row reduction + in-block sum (r11/r19 form, proven fast).
__global__ __launch_bounds__(256) void rowred_kernel(
    const float* __restrict__ partial, float* __restrict__ bsum)
{
    const int t   = threadIdx.x;
    const int row = blockIdx.x * 256 + t;

    float P = 0.f;
#pragma unroll
    for (int s = 0; s < NJSLAB_POS; ++s) P += partial[(size_t)s * N_POS + row];

    float a0 = 0.f, a1 = 0.f, a2 = 0.f, a3 = 0.f;
    for (int s0 = NJSLAB_POS; s0 < NJSLAB; s0 += 16) {
        float v[16];
#pragma unroll
        for (int i = 0; i < 16; ++i)
            v[i] = partial[(size_t)(s0 + i) * N_POS + row];
#pragma unroll
        for (int i = 0; i < 16; i += 4) {
            a0 += v[i]; a1 += v[i + 1]; a2 += v[i + 2]; a3 += v[i + 3];
        }
    }
    const float Nv = (a0 + a1) + (a2 + a3);

    const float p = P - 2.71828182845904523536f;   // remove self-sim exp(1)
    const float term = logf(p) - logf(p + Nv);

    __shared__ float red[256];
    red[t] = term;
    __syncthreads();
    for (int s = 128; s > 0; s >>= 1) {
        if (t < s) red[t] += red[t + s];
        __syncthreads();
    }
    if (t == 0) bsum[blockIdx.x] = red[0];
}

// Kernel 3b: sum the 8 block sums. Single wave, deterministic.
__global__ __launch_bounds__(64) void final_kernel(
    const float* __restrict__ bsum, float* __restrict__ out)
{
    if (threadIdx.x == 0) {
        float s = 0.f;
#pragma unroll
        for (int i = 0; i < N_POS / 256; ++i) s += bsum[i];
        out[0] = -s / (float)N_POS;
    }
}

// ---------------------------------------------------------------------------
extern "C" void kernel_launch(void* const* d_in, const int* in_sizes, int n_in,
                              void* d_out, int out_size, void* d_ws, size_t ws_size,
                              hipStream_t stream)
{
    const float* seg = (const float*)d_in[0];
    const int* pb = (const int*)d_in[1];
    const int* ph = (const int*)d_in[2];
    const int* pw = (const int*)d_in[3];
    const int* nb = (const int*)d_in[4];
    const int* nh = (const int*)d_in[5];
    const int* nw = (const int*)d_in[6];
    float* out = (float*)d_out;

    ushort* hi_t = (ushort*)d_ws;
    ushort* lo_t = hi_t + (size_t)N_ROWS * C_CH;
    float* partial = (float*)(lo_t + (size_t)N_ROWS * C_CH);
    float* bsum    = partial + (size_t)NJSLAB * N_POS;

    gather_norm_kernel<<<dim3((N_ROWS + 3) / 4), dim3(256), 0, stream>>>(
        seg, pb, ph, pw, nb, nh, nw, hi_t, lo_t);

    sim_mfma_kernel<<<dim3(NIG * NJG), dim3(512), 0, stream>>>(hi_t, lo_t, partial);

    rowred_kernel<<<dim3(N_POS / 256), dim3(256), 0, stream>>>(partial, bsum);
    final_kernel<<<dim3(1), dim3(64), 0, stream>>>(bsum, out);
}

// Round 22
// 59.747 us; speedup vs baseline: 1.1813x; 1.1813x over previous
//
#include <hip/hip_runtime.h>
#include <hip/hip_bf16.h>
#include <math.h>

// Problem constants (match reference)
#define BB      8
#define C_CH    128
#define HH      256
#define WW      256
#define N_POS   2048
#define N_NEG   8192
#define N_ROWS  (N_POS + N_NEG)     // 10240
#define EPS_N   1e-6f

// sim tiling (r19 form, 63.3us measured best): block = 4 waves, each wave a
// DISTINCT 64-row i-tile (256 rows/block), sharing one 64-col j-slab staged
// to LDS once (32 KB, single barrier).
#define NIG     (N_POS / 256)       // 8  i-groups
#define NJS     (N_ROWS / 64)       // 160 j-slabs
#define NJSLAB      (N_ROWS / 64)   // 160
#define NJSLAB_POS  (N_POS / 64)    // 32

// Fragment-swizzled operand layout (r17, confirmed win):
#define PANEL   512                  // shorts per (tile,ks) panel

typedef __attribute__((ext_vector_type(8))) short bf16x8;
typedef __attribute__((ext_vector_type(4))) float f32x4;

// Workspace:
//   hi_t: [640][4][64][8] bf16 (2.62 MB) | lo_t: same | partial (1.31 MB)
//   bsum[8] f32

// ---------------------------------------------------------------------------
// Kernel 1: gather + L2-normalize + split to bf16 hi/lo (swizzled out).
// UNCHANGED (r17/r19 form).
__global__ __launch_bounds__(256) void gather_norm_kernel(
    const float* __restrict__ seg,
    const int* __restrict__ pb, const int* __restrict__ ph, const int* __restrict__ pw,
    const int* __restrict__ nb, const int* __restrict__ nh, const int* __restrict__ nw,
    ushort* __restrict__ hi_t, ushort* __restrict__ lo_t)
{
    const int wave = threadIdx.x >> 6;
    const int lane = threadIdx.x & 63;
    const int row  = blockIdx.x * 4 + wave;
    if (row >= N_ROWS) return;

    int b, h, w;
    if (row < N_POS) { b = pb[row]; h = ph[row]; w = pw[row]; }
    else { const int r = row - N_POS; b = nb[r]; h = nh[r]; w = nw[r]; }

    const size_t cs   = (size_t)HH * WW;
    const size_t base = (size_t)b * C_CH * cs + (size_t)h * WW + (size_t)w;

    const float v0 = seg[base + (size_t)lane * cs];
    const float v1 = seg[base + (size_t)(lane + 64) * cs];

    float ss = v0 * v0 + v1 * v1;
#pragma unroll
    for (int m = 1; m < 64; m <<= 1) ss += __shfl_xor(ss, m, 64);

    const float n  = fmaxf(sqrtf(ss), EPS_N);
    const float u0 = v0 / n;
    const float u1 = v1 / n;

    const __hip_bfloat16 h0 = __float2bfloat16(u0);
    const __hip_bfloat16 h1 = __float2bfloat16(u1);
    const __hip_bfloat16 l0 = __float2bfloat16(u0 - __bfloat162float(h0));
    const __hip_bfloat16 l1 = __float2bfloat16(u1 - __bfloat162float(h1));

    const int tile = row >> 4;
    const int lr   = row & 15;

    const int e0 = lane;
    const int ks0 = e0 >> 5, lk0 = (e0 & 31) >> 3, ke0 = e0 & 7;
    const size_t o0 = ((size_t)(tile * 4 + ks0) * 64 + lk0 * 16 + lr) * 8 + ke0;

    const int e1 = lane + 64;
    const int ks1 = e1 >> 5, lk1 = (e1 & 31) >> 3, ke1 = e1 & 7;
    const size_t o1 = ((size_t)(tile * 4 + ks1) * 64 + lk1 * 16 + lr) * 8 + ke1;

    hi_t[o0] = __hip_bfloat16_raw(h0).x;  lo_t[o0] = __hip_bfloat16_raw(l0).x;
    hi_t[o1] = __hip_bfloat16_raw(h1).x;  lo_t[o1] = __hip_bfloat16_raw(l1).x;
}

// ---------------------------------------------------------------------------
// Kernel 2: split-bf16 MFMA sim with LDS-staged B j-slab (r19 structure).
// ONE CHANGE: expf -> __expf in the epilogue (native v_exp_f32; r18 probe
// showed VALUBusy 26% > MfmaUtil 15.5%, and the epilogue's 64 libm expf
// (~2600 cyc/wave) is sim's only heavy VALU code).
__global__ __launch_bounds__(256) void sim_mfma_kernel(
    const ushort* __restrict__ hi_t, const ushort* __restrict__ lo_t,
    float* __restrict__ partial)
{
    __shared__ ushort ldsB[2][8192];    // [hi/lo][16 KB] = 32 KB

    const int bid = blockIdx.x;
    const int ig  = bid / NJS;          // 0..7
    const int js  = bid % NJS;          // 0..159 (same-js blocks == mod 8 -> same XCD)
    const int t    = threadIdx.x;
    const int wv   = t >> 6;
    const int ln   = t & 63;

    {
        const size_t gb = (size_t)js * 8192;
#pragma unroll
        for (int c = 0; c < 4; ++c) {
            const int off = (c * 256 + t) * 8;
            *(bf16x8*)&ldsB[0][off] = *(const bf16x8*)&hi_t[gb + off];
            *(bf16x8*)&ldsB[1][off] = *(const bf16x8*)&lo_t[gb + off];
        }
    }
    __syncthreads();

    const int iw0 = ig * 256 + wv * 64;
    const int lr = ln & 15;
    const int lk = ln >> 4;

    f32x4 acc[4][4];
#pragma unroll
    for (int m = 0; m < 4; ++m)
#pragma unroll
        for (int n = 0; n < 4; ++n) acc[m][n] = (f32x4){0.f, 0.f, 0.f, 0.f};

#pragma unroll
    for (int ks = 0; ks < 4; ++ks) {
        bf16x8 ah[4], al[4], bh[4], bl[4];
#pragma unroll
        for (int m = 0; m < 4; ++m) {
            const size_t pa = ((size_t)((ig * 16 + wv * 4 + m) * 4 + ks)) * PANEL + ln * 8;
            ah[m] = *(const bf16x8*)&hi_t[pa];
            al[m] = *(const bf16x8*)&lo_t[pa];
        }
#pragma unroll
        for (int n = 0; n < 4; ++n) {
            const int lo_off = (n * 4 + ks) * PANEL + ln * 8;
            bh[n] = *(const bf16x8*)&ldsB[0][lo_off];
            bl[n] = *(const bf16x8*)&ldsB[1][lo_off];
        }

#pragma unroll
        for (int n = 0; n < 4; ++n) {
#pragma unroll
            for (int m = 0; m < 4; ++m) {
                acc[m][n] = __builtin_amdgcn_mfma_f32_16x16x32_bf16(ah[m], bh[n], acc[m][n], 0, 0, 0);
                acc[m][n] = __builtin_amdgcn_mfma_f32_16x16x32_bf16(ah[m], bl[n], acc[m][n], 0, 0, 0);
                acc[m][n] = __builtin_amdgcn_mfma_f32_16x16x32_bf16(al[m], bh[n], acc[m][n], 0, 0, 0);
            }
        }
    }

    // Epilogue (native exp). value r of lane l = C[iw0+m*16+(l>>4)*4+r][...]
#pragma unroll
    for (int m = 0; m < 4; ++m) {
        float s0 = 0.f, s1 = 0.f, s2 = 0.f, s3 = 0.f;
#pragma unroll
        for (int n = 0; n < 4; ++n) {
            s0 += __expf(acc[m][n][0]);
            s1 += __expf(acc[m][n][1]);
            s2 += __expf(acc[m][n][2]);
            s3 += __expf(acc[m][n][3]);
        }
        float s[4] = {s0, s1, s2, s3};
#pragma unroll
        for (int r = 0; r < 4; ++r) {
            float v = s[r];
            v += __shfl_xor(v, 1, 64);
            v += __shfl_xor(v, 2, 64);
            v += __shfl_xor(v, 4, 64);
            v += __shfl_xor(v, 8, 64);
            if (lr == 0) {
                const int row = iw0 + m * 16 + lk * 4 + r;
                partial[(size_t)js * N_POS + row] = v;   // single writer
            }
        }
    }
}

// ---------------------------------------------------------------------------
// Kernel 3a: per-row reduction + in-block sum (r11/r19 form, proven fast).
__global__ __launch_bounds__(256) void rowred_kernel(
    const float* __restrict__ partial, float* __restrict__ bsum)
{
    const int t   = threadIdx.x;
    const int row = blockIdx.x * 256 + t;

    float P = 0.f;
#pragma unroll
    for (int s = 0; s < NJSLAB_POS; ++s) P += partial[(size_t)s * N_POS + row];

    float a0 = 0.f, a1 = 0.f, a2 = 0.f, a3 = 0.f;
    for (int s0 = NJSLAB_POS; s0 < NJSLAB; s0 += 16) {
        float v[16];
#pragma unroll
        for (int i = 0; i < 16; ++i)
            v[i] = partial[(size_t)(s0 + i) * N_POS + row];
#pragma unroll
        for (int i = 0; i < 16; i += 4) {
            a0 += v[i]; a1 += v[i + 1]; a2 += v[i + 2]; a3 += v[i + 3];
        }
    }
    const float Nv = (a0 + a1) + (a2 + a3);

    const float p = P - 2.71828182845904523536f;   // remove self-sim exp(1)
    const float term = logf(p) - logf(p + Nv);

    __shared__ float red[256];
    red[t] = term;
    __syncthreads();
    for (int s = 128; s > 0; s >>= 1) {
        if (t < s) red[t] += red[t + s];
        __syncthreads();
    }
    if (t == 0) bsum[blockIdx.x] = red[0];
}

// Kernel 3b: sum the 8 block sums. Single wave, deterministic.
__global__ __launch_bounds__(64) void final_kernel(
    const float* __restrict__ bsum, float* __restrict__ out)
{
    if (threadIdx.x == 0) {
        float s = 0.f;
#pragma unroll
        for (int i = 0; i < N_POS / 256; ++i) s += bsum[i];
        out[0] = -s / (float)N_POS;
    }
}

// ---------------------------------------------------------------------------
extern "C" void kernel_launch(void* const* d_in, const int* in_sizes, int n_in,
                              void* d_out, int out_size, void* d_ws, size_t ws_size,
                              hipStream_t stream)
{
    const float* seg = (const float*)d_in[0];
    const int* pb = (const int*)d_in[1];
    const int* ph = (const int*)d_in[2];
    const int* pw = (const int*)d_in[3];
    const int* nb = (const int*)d_in[4];
    const int* nh = (const int*)d_in[5];
    const int* nw = (const int*)d_in[6];
    float* out = (float*)d_out;

    ushort* hi_t = (ushort*)d_ws;
    ushort* lo_t = hi_t + (size_t)N_ROWS * C_CH;
    float* partial = (float*)(lo_t + (size_t)N_ROWS * C_CH);
    float* bsum    = partial + (size_t)NJSLAB * N_POS;

    gather_norm_kernel<<<dim3((N_ROWS + 3) / 4), dim3(256), 0, stream>>>(
        seg, pb, ph, pw, nb, nh, nw, hi_t, lo_t);

    sim_mfma_kernel<<<dim3(NIG * NJS), dim3(256), 0, stream>>>(hi_t, lo_t, partial);

    rowred_kernel<<<dim3(N_POS / 256), dim3(256), 0, stream>>>(partial, bsum);
    final_kernel<<<dim3(1), dim3(64), 0, stream>>>(bsum, out);
}